// Round 1
// baseline (247.662 us; speedup 1.0000x reference)
//
#include <hip/hip_runtime.h>
#include <math.h>

#define PI_D 3.14159265358979323846

// ---------------- scatter: remap + gaussian gridding (w channel only) ----------------
__global__ void k_scatter(const float* __restrict__ inp,
                          const float* __restrict__ p_scale,
                          const float* __restrict__ p_sigma,
                          const float* __restrict__ p_A,
                          const float* __restrict__ p_ic,
                          float* __restrict__ ft) {
  int i = blockIdx.x * 256 + threadIdx.x;           // 0 .. 262143
  double scale = (double)p_scale[0];
  double sigma = (double)p_sigma[0];
  double A     = (double)p_A[0];
  double icomp = (double)p_ic[0];
  int b = i >> 15;
  double x = (double)inp[i*3+0];
  double y = (double)inp[i*3+1];
  double z = (double)inp[i*3+2];
  double r = sqrt(x*x + y*y + z*z);
  if (r < 0.1) r = 0.1;
  double ctv = z / r;
  ctv = fmin(fmax(ctv, -1.0), 1.0);
  double theta = acos(ctv);
  double phi = atan2(y, x) + PI_D;
  double ct = theta / PI_D * 32.0;
  double cp = phi / (2.0 * PI_D) * 32.0;
  double cr = r / scale * 8.0;
  int it = (int)floor(ct); it = min(max(it, 0), 31);
  int ip = (int)floor(cp); ip = min(max(ip, 0), 31);
  int ir = (int)floor(cr); ir = min(max(ir, 0), 7);
  double dt = ct - ((double)it + icomp);
  double dp = cp - ((double)ip + icomp);
  double dr = cr - ((double)ir + icomp);
  double d2 = dt*dt + dp*dp + dr*dr;
  float w = (float)(A * exp(-d2 / (2.0 * sigma * sigma)));
  // ft layout: (b, ir, it, ip)  == transpose(grid[...,0],(0,3,1,2))
  atomicAdd(&ft[((b*8 + ir)*32 + it)*32 + ip], w);
}

// ---------------- conv1: (8,8,32,32) -> (8,32,32,32), 3x3 SAME + relu ----------------
__global__ void k_conv1(const float* __restrict__ ft, const float* __restrict__ W,
                        const float* __restrict__ bias, float* __restrict__ h1) {
  int blk = blockIdx.x;            // 256 = b(8) * oc(32)
  int b = blk >> 5, oc = blk & 31;
  __shared__ float Ws[72];
  int t = threadIdx.x;             // 1024
  if (t < 72) Ws[t] = W[oc*72 + t];
  __syncthreads();
  int x = t >> 5, y = t & 31;
  float acc = bias[oc];
  const float* fb = ft + b*8192;
  for (int ic = 0; ic < 8; ++ic) {
    const float* fc = fb + ic*1024;
    const float* wr = Ws + ic*9;
#pragma unroll
    for (int dx = -1; dx <= 1; ++dx) {
      int xx = x + dx;
      bool okx = ((unsigned)xx < 32u);
#pragma unroll
      for (int dy = -1; dy <= 1; ++dy) {
        int yy = y + dy;
        float v = (okx && ((unsigned)yy < 32u)) ? fc[xx*32 + yy] : 0.f;
        acc = fmaf(v, wr[(dx+1)*3 + (dy+1)], acc);
      }
    }
  }
  h1[(b*32 + oc)*1024 + t] = fmaxf(acc, 0.f);
}

// ---------------- conv2: (8,32,32,32) -> (8,64,32,32), 3x3 SAME + relu ----------------
__global__ __launch_bounds__(512) void k_conv2(const float* __restrict__ h1,
                        const float* __restrict__ W,
                        const float* __restrict__ bias, float* __restrict__ h2) {
  int blk = blockIdx.x;            // 256 = b(8) * q(32);  q = ocquad(16) * xhalf(2)
  int b = blk >> 5, q = blk & 31;
  int oc0 = (q >> 1) * 4, xh = q & 1;
  __shared__ float Ws[4*288];
  int t = threadIdx.x;             // 512
  for (int idx = t; idx < 4*288; idx += 512) Ws[idx] = W[oc0*288 + idx];
  __syncthreads();
  int x = xh*16 + (t >> 5), y = t & 31;
  float a0 = bias[oc0+0], a1 = bias[oc0+1], a2 = bias[oc0+2], a3 = bias[oc0+3];
  const float* hb = h1 + b*32*1024;
  for (int ic = 0; ic < 32; ++ic) {
    const float* hc = hb + ic*1024;
    const float* w0 = Ws + 0*288 + ic*9;
    const float* w1 = Ws + 1*288 + ic*9;
    const float* w2 = Ws + 2*288 + ic*9;
    const float* w3 = Ws + 3*288 + ic*9;
#pragma unroll
    for (int dx = -1; dx <= 1; ++dx) {
      int xx = x + dx;
      bool okx = ((unsigned)xx < 32u);
#pragma unroll
      for (int dy = -1; dy <= 1; ++dy) {
        int yy = y + dy;
        float v = (okx && ((unsigned)yy < 32u)) ? hc[xx*32 + yy] : 0.f;
        int k = (dx+1)*3 + (dy+1);
        a0 = fmaf(v, w0[k], a0);
        a1 = fmaf(v, w1[k], a1);
        a2 = fmaf(v, w2[k], a2);
        a3 = fmaf(v, w3[k], a3);
      }
    }
  }
  int p = x*32 + y;
  h2[(b*64 + oc0+0)*1024 + p] = fmaxf(a0, 0.f);
  h2[(b*64 + oc0+1)*1024 + p] = fmaxf(a1, 0.f);
  h2[(b*64 + oc0+2)*1024 + p] = fmaxf(a2, 0.f);
  h2[(b*64 + oc0+3)*1024 + p] = fmaxf(a3, 0.f);
}

// ---------------- reduce: ft_max[b,c] = (sum_g Wg[c,g]) * sum_{x,y} h2*wq[y] ----------------
__global__ void k_reduce(const float* __restrict__ h2, const float* __restrict__ Wg,
                         float* __restrict__ ftmax) {
  int blk = blockIdx.x;            // 512 = b(8)*c(64)
  int b = blk >> 6, c = blk & 63;
  __shared__ float wqs[32];
  __shared__ float red[256];
  int t = threadIdx.x;             // 256
  if (t < 32) {
    // Driscoll-Healy weights, bw=16, computed in double (matches np float64)
    double jj = 2.0*(double)t + 1.0;
    double theta = PI_D * jj / 64.0;
    double s = 0.0;
    for (int k = 0; k < 16; ++k)
      s += sin(jj * (double)(2*k+1) * PI_D / 64.0) / (double)(2*k+1);
    wqs[t] = (float)((2.0/16.0) * sin(theta) * s);
  }
  __syncthreads();
  const float* hb = h2 + (b*64 + c)*1024;
  float acc = 0.f;
  for (int i = t; i < 1024; i += 256) acc = fmaf(hb[i], wqs[i & 31], acc);
  red[t] = acc;
  __syncthreads();
  for (int s2 = 128; s2 > 0; s2 >>= 1) {
    if (t < s2) red[t] += red[t + s2];
    __syncthreads();
  }
  if (t == 0) {
    float sg = 0.f;
    for (int g = 0; g < 32; ++g) sg += Wg[c*32 + g];
    ftmax[b*64 + c] = sg * red[0];
  }
}

// ---------------- head: h3 = relu(h2*Wg ⊗ Wc31 + K), out = h3*Wc32^T + b ----------------
__global__ __launch_bounds__(512) void k_head(
    const float* __restrict__ h2, const float* __restrict__ ftmax,
    const float* __restrict__ Wc31, const float* __restrict__ bc31,
    const float* __restrict__ Wc32, const float* __restrict__ bc32,
    const float* __restrict__ Wg, float* __restrict__ out,
    float* __restrict__ blockmax) {
  __shared__ float h2s[32*65];                    // [y][c] (+pad)
  __shared__ float Wgst[32*64];                   // [g][c]
  __shared__ __align__(16) float Ut[64*64];       // [c][d]  (float4 over d)
  __shared__ float W2s[64*32];                    // [d][e]
  __shared__ __align__(16) float h3s[2*32*64];    // [gg][y][d]
  __shared__ float Ks[64];
  __shared__ float b2s[32];
  __shared__ float vbuf[512];
  int blk = blockIdx.x;            // 256 = b(8)*x(32)
  int b = blk >> 5, x = blk & 31;
  int t = threadIdx.x;             // 512

  for (int idx = t; idx < 2048; idx += 512) {
    int y = idx & 31, c = idx >> 5;
    h2s[y*65 + c] = h2[(b*64 + c)*1024 + x*32 + y];
  }
  for (int idx = t; idx < 2048; idx += 512) {
    int c = idx & 63, g = idx >> 6;
    Wgst[g*64 + c] = Wg[c*32 + g];
  }
  for (int idx = t; idx < 4096; idx += 512) {
    int d = idx & 63, c = idx >> 6;
    Ut[idx] = Wc31[d*128 + c];
  }
  for (int idx = t; idx < 2048; idx += 512) {
    int e = idx & 31, d = idx >> 5;
    W2s[idx] = Wc32[e*64 + d];
  }
  if (t < 64) {
    float acc = bc31[t];
    for (int c = 0; c < 64; ++c)
      acc = fmaf(Wc31[t*128 + 64 + c], ftmax[b*64 + c], acc);
    Ks[t] = acc;
  }
  if (t < 32) b2s[t] = bc32[t];
  __syncthreads();

  const int dt = t & 15, d4 = dt*4;
  const int ytA = (t >> 4) & 15, y2a = ytA*2;
  const int gp = t >> 8;           // 0/1
  const int e = t & 31;
  const int y2b = (t >> 5) * 2;
  const float4* Ut4 = (const float4*)Ut;
  const float kx_ = Ks[d4], ky_ = Ks[d4+1], kz_ = Ks[d4+2], kw_ = Ks[d4+3];
  const float bb = b2s[e];
  float vmax = -3.4e38f;

  for (int gq = 0; gq < 16; ++gq) {
    int g0 = gq * 2;
    // ---- phase A: h3 for g in {g0, g0+1} ----
    {
      int g = g0 + gp;
      float4 acc0 = make_float4(kx_, ky_, kz_, kw_);
      float4 acc1 = acc0;
      const float* h2rA = h2s + y2a*65;
      const float* h2rB = h2s + (y2a+1)*65;
      const float* wgr  = Wgst + g*64;
      for (int c = 0; c < 64; ++c) {
        float4 u = Ut4[c*16 + dt];
        float wg = wgr[c];
        float a0 = h2rA[c] * wg;
        float a1 = h2rB[c] * wg;
        acc0.x = fmaf(a0, u.x, acc0.x); acc0.y = fmaf(a0, u.y, acc0.y);
        acc0.z = fmaf(a0, u.z, acc0.z); acc0.w = fmaf(a0, u.w, acc0.w);
        acc1.x = fmaf(a1, u.x, acc1.x); acc1.y = fmaf(a1, u.y, acc1.y);
        acc1.z = fmaf(a1, u.z, acc1.z); acc1.w = fmaf(a1, u.w, acc1.w);
      }
      acc0.x = fmaxf(acc0.x, 0.f); acc0.y = fmaxf(acc0.y, 0.f);
      acc0.z = fmaxf(acc0.z, 0.f); acc0.w = fmaxf(acc0.w, 0.f);
      acc1.x = fmaxf(acc1.x, 0.f); acc1.y = fmaxf(acc1.y, 0.f);
      acc1.z = fmaxf(acc1.z, 0.f); acc1.w = fmaxf(acc1.w, 0.f);
      *(float4*)&h3s[(gp*32 + y2a  )*64 + d4] = acc0;
      *(float4*)&h3s[(gp*32 + y2a+1)*64 + d4] = acc1;
    }
    __syncthreads();
    // ---- phase B: out[e, y, g0..g0+1] ----
    {
      float b00 = bb, b10 = bb, b01 = bb, b11 = bb;   // [yy][gg]
      const float* h3r0 = h3s + (0*32 + y2b  )*64;    // gg=0, yy=0
      const float* h3r1 = h3s + (0*32 + y2b+1)*64;    // gg=0, yy=1
      const float* h3r2 = h3s + (1*32 + y2b  )*64;    // gg=1, yy=0
      const float* h3r3 = h3s + (1*32 + y2b+1)*64;    // gg=1, yy=1
      for (int d = 0; d < 64; ++d) {
        float w2 = W2s[d*32 + e];
        b00 = fmaf(h3r0[d], w2, b00);
        b10 = fmaf(h3r2[d], w2, b10);
        b01 = fmaf(h3r1[d], w2, b01);
        b11 = fmaf(h3r3[d], w2, b11);
      }
      float2 o0 = make_float2(b00, b10);
      float2 o1 = make_float2(b01, b11);
      *(float2*)&out[(((b*32 + e)*32 + x)*32 + (y2b  ))*32 + g0] = o0;
      *(float2*)&out[(((b*32 + e)*32 + x)*32 + (y2b+1))*32 + g0] = o1;
      vmax = fmaxf(vmax, fmaxf(fmaxf(b00, b01), fmaxf(b10, b11)));
    }
    __syncthreads();
  }
  vbuf[t] = vmax;
  __syncthreads();
  if (t < 32) {
    float m = vbuf[t];
    for (int j = 1; j < 16; ++j) m = fmaxf(m, vbuf[t + 32*j]);
    blockmax[blk*32 + t] = m;
  }
}

// ---------------- finalize: ft_g[b,e] = max over x of blockmax ----------------
__global__ void k_final(const float* __restrict__ blockmax, float* __restrict__ ftg) {
  int t = threadIdx.x;             // 256 = b(8)*e(32)
  int b = t >> 5, e = t & 31;
  float m = -3.4e38f;
  for (int x = 0; x < 32; ++x) m = fmaxf(m, blockmax[(b*32 + x)*32 + e]);
  ftg[b*32 + e] = m;
}

extern "C" void kernel_launch(void* const* d_in, const int* in_sizes, int n_in,
                              void* d_out, int out_size, void* d_ws, size_t ws_size,
                              hipStream_t stream) {
  const float* inputs = (const float*)d_in[0];
  const float* scale  = (const float*)d_in[1];
  const float* sigma  = (const float*)d_in[2];
  const float* A      = (const float*)d_in[3];
  const float* icmp   = (const float*)d_in[4];
  // d_in[5]=res_pt(32), d_in[6]=res_r(8) — compile-time constants here
  const float* W1   = (const float*)d_in[7];
  const float* b1   = (const float*)d_in[8];
  const float* W2   = (const float*)d_in[9];
  const float* b2   = (const float*)d_in[10];
  const float* Wg   = (const float*)d_in[11];
  const float* Wc31 = (const float*)d_in[12];
  const float* bc31 = (const float*)d_in[13];
  const float* Wc32 = (const float*)d_in[14];
  const float* bc32 = (const float*)d_in[15];

  float* ws    = (float*)d_ws;
  float* ft    = ws;               // 65536
  float* h1    = ws + 65536;       // 262144
  float* h2    = ws + 327680;      // 524288
  float* ftmax = ws + 851968;      // 512
  float* bmax  = ws + 852480;      // 8192
  float* out   = (float*)d_out;    // 8388608
  float* ftg   = out + 8388608;    // 256

  hipMemsetAsync(ft, 0, 65536*sizeof(float), stream);
  k_scatter<<<1024, 256, 0, stream>>>(inputs, scale, sigma, A, icmp, ft);
  k_conv1<<<256, 1024, 0, stream>>>(ft, W1, b1, h1);
  k_conv2<<<256, 512, 0, stream>>>(h1, W2, b2, h2);
  k_reduce<<<512, 256, 0, stream>>>(h2, Wg, ftmax);
  k_head<<<256, 512, 0, stream>>>(h2, ftmax, Wc31, bc31, Wc32, bc32, Wg, out, bmax);
  k_final<<<1, 256, 0, stream>>>(bmax, ftg);
}